// Round 7
// baseline (82417.780 us; speedup 1.0000x reference)
//
#include <hip/hip_runtime.h>

#define NB 8192
#define NH 128
#define NLB 64
#define NPW 32
#define MAGIC 1234567
#define SP 136                      // LDS stride (bf16): 272B rows, 16B-aligned

typedef __attribute__((ext_vector_type(8))) __bf16 bf16x8;
typedef __attribute__((ext_vector_type(4))) __bf16 bf16x4;
typedef __attribute__((ext_vector_type(4))) float f32x4;

__device__ __forceinline__ f32x4 mfma3(bf16x8 ah, bf16x8 al, bf16x8 bh, bf16x8 bl, f32x4 c) {
    c = __builtin_amdgcn_mfma_f32_16x16x32_bf16(ah, bh, c, 0, 0, 0);
    c = __builtin_amdgcn_mfma_f32_16x16x32_bf16(ah, bl, c, 0, 0, 0);
    c = __builtin_amdgcn_mfma_f32_16x16x32_bf16(al, bh, c, 0, 0, 0);
    return c;
}

__device__ __forceinline__ void ld_split8(const float* p, bf16x8& h, bf16x8& l) {
    float vv[8];
    *(float4*)vv       = *(const float4*)p;
    *(float4*)(vv + 4) = *(const float4*)(p + 4);
#pragma unroll
    for (int j = 0; j < 8; ++j) {
        __bf16 t = (__bf16)vv[j];
        h[j] = t;
        l[j] = (__bf16)(vv[j] - (float)t);
    }
}

// ws float offsets
#define KT_OFF   560                  // 64*128 k-table
#define g63_OFF  (KT_OFF + 8192)
#define MR_OFF   (g63_OFF + 128)      // legacy (unused)
#define DV_OFF   (MR_OFF + 2048)
#define DP_OFF   (DV_OFF + 32)
#define UV_OFF   (DP_OFF + 32)        // 32*128 u-vectors
#define XC_OFF   16000                // 64*128 X-columns
#define SINK_OFF 32000
#define FLAG_I   34000                // int index; FLAG_I = DONE counter
#define SFLAG_I  (FLAG_I + 1600)      // per-step flags: SFLAG_I + t*16
#define FHI_OFF  40960                // bf16 hi of F[0..63]
#define FLO_OFF  (FHI_OFF + 524288)
#define WS_SPLIT_BYTES  ((size_t)(FLO_OFF + 524288) * 4)

#define DYN_LDS  ((144 + 144 + 128 + 128) * SP * 2)   // 147968 B

#define AGLD(idx)  __hip_atomic_load(&ws[idx], __ATOMIC_RELAXED, __HIP_MEMORY_SCOPE_AGENT)
#define AGST(idx, v) __hip_atomic_store(&ws[idx], (v), __ATOMIC_RELAXED, __HIP_MEMORY_SCOPE_AGENT)

// ========== K0: pre-split F[t<64] into bf16 hi/lo ===========================
__global__ __launch_bounds__(256)
void k0_split(const float* __restrict__ F, float* __restrict__ ws)
{
    size_t e = ((size_t)blockIdx.x * 256 + threadIdx.x) * 8;
    __bf16* fh = (__bf16*)(ws + FHI_OFF);
    __bf16* fl = (__bf16*)(ws + FLO_OFF);
    float v[8];
    *(float4*)v       = *(const float4*)(F + e);
    *(float4*)(v + 4) = *(const float4*)(F + e + 4);
    bf16x8 h, l;
#pragma unroll
    for (int j = 0; j < 8; ++j) {
        __bf16 t = (__bf16)v[j];
        h[j] = t;
        l[j] = (__bf16)(v[j] - (float)t);
    }
    *(bf16x8*)&fh[e] = h;
    *(bf16x8*)&fl[e] = l;
}

// ========== K1: recursion + u-chains + columns + fused k3 + burners =========
__global__ __launch_bounds__(1024) __attribute__((amdgpu_waves_per_eu(4, 4)))
void k1_recur(const float* __restrict__ Fw,
              const float* __restrict__ Fb,
              const float* __restrict__ Hw,
              const float* __restrict__ Hb,
              const float* __restrict__ init_state,
              const float* __restrict__ init_cov,
              const float* __restrict__ Qm,
              const float* __restrict__ Rm,
              const float* __restrict__ x,
              float* __restrict__ out,
              float* __restrict__ ws,
              int use_split)
{
    const int tid = threadIdx.x;
    const int wg  = blockIdx.x;
    int* wsl = (int*)ws;

    extern __shared__ __align__(16) char dsm[];
    __bf16* PhiS = (__bf16*)dsm;                 // X hi: [144][SP] (rows 128..130 = w,k,g)
    __bf16* PloS = PhiS + 144 * SP;
    __bf16* UhiS = PloS + 144 * SP;              // U^T hi: [c:128][i:SP]
    __bf16* UloS = UhiS + 128 * SP;

    __shared__ float smisc[1280];                // pV[640] | pW[640]; u-chain partials
    __shared__ __align__(16) float shHb[2][NH];  // columns: shX/shY
    __shared__ __align__(16) float shH[NH];
    __shared__ __align__(16) float shFW[NH];
    __shared__ float shK[NH], shV[NH], shFV[NH], shG[NH], shGn[NH];
    __shared__ float scal[16];

    float* pV = smisc;            // [r*5 + a]
    float* pW = smisc + 640;      // [c*5 + b]

    if (wg == 0) {
        const float Rv = Rm[0];
        const int lane = tid & 63, w = tid >> 6;
        const int lm = lane & 15, kg = lane >> 4;
        const int a = w >> 2, b = w & 3;          // 4x4 wave grid
        const int arow = a * 32, bcol = b * 32;

        // ---- init: X rows 0..127 = init_cov (hi/lo) ----
#pragma unroll
        for (int ii = 0; ii < 16; ++ii) {
            int e = tid + ii * 1024;
            int r = e >> 7, c = e & 127;
            float v = init_cov[e];
            __bf16 h = (__bf16)v;
            PhiS[r * SP + c] = h;
            PloS[r * SP + c] = (__bf16)(v - (float)h);
        }
        // ---- init: X rows 128..143: w=0, k=0, g=init_state, rest 0 ----
#pragma unroll
        for (int ii = 0; ii < 2; ++ii) {
            int e = tid + ii * 1024;
            int r = 128 + (e >> 7), c = e & 127;
            float v = (r == 130) ? init_state[c] : 0.f;
            __bf16 h = (__bf16)v;
            PhiS[r * SP + c] = h;
            PloS[r * SP + c] = (__bf16)(v - (float)h);
        }
        if (tid < NH) shG[tid] = init_state[tid];
        if (tid == 0) scal[1] = 0.f;

        // Q tile in registers (phase-B output map).
        f32x4 qreg[2][2];
#pragma unroll
        for (int rt2 = 0; rt2 < 2; ++rt2)
#pragma unroll
            for (int ct2 = 0; ct2 < 2; ++ct2)
                qreg[rt2][ct2] =
                    *(const f32x4*)&Qm[(bcol + rt2 * 16 + lm) * 128 + arow + ct2 * 16 + kg * 4];

        // F fragments, rotated: holds F(t) entering each iteration.
        bf16x8 fbH[2][4], fbL[2][4];
#define LOADF(tt)                                                               \
        if (use_split) {                                                        \
            const __bf16* fh_ = (const __bf16*)(ws + FHI_OFF) + (size_t)(tt) * 16384; \
            const __bf16* fl_ = (const __bf16*)(ws + FLO_OFF) + (size_t)(tt) * 16384; \
            _Pragma("unroll")                                                   \
            for (int rs_ = 0; rs_ < 2; ++rs_)                                   \
                _Pragma("unroll")                                               \
                for (int kc_ = 0; kc_ < 4; ++kc_) {                             \
                    int ro_ = (bcol + rs_ * 16 + lm) * 128 + kc_ * 32 + kg * 8; \
                    fbH[rs_][kc_] = *(const bf16x8*)&fh_[ro_];                  \
                    fbL[rs_][kc_] = *(const bf16x8*)&fl_[ro_];                  \
                }                                                               \
        } else {                                                                \
            const float* Ft_ = Fw + (size_t)(tt) * 16384;                       \
            _Pragma("unroll")                                                   \
            for (int rs_ = 0; rs_ < 2; ++rs_)                                   \
                _Pragma("unroll")                                               \
                for (int kc_ = 0; kc_ < 4; ++kc_)                               \
                    ld_split8(Ft_ + (bcol + rs_ * 16 + lm) * 128 + kc_ * 32 + kg * 8, \
                              fbH[rs_][kc_], fbL[rs_][kc_]);                    \
        }
        LOADF(0)
        __syncthreads();

        for (int t = 0; t < NLB; ++t) {
            // publish kt[t-1] (ordered by the loop-end barrier of step t-1)
            if (t && tid == 512)
                __hip_atomic_store(&wsl[SFLAG_I + (t - 1) * 16], MAGIC,
                                   __ATOMIC_RELEASE, __HIP_MEMORY_SCOPE_AGENT);

            // ================= phase A: U = X F^T (U^T -> LDS) =================
            float fbv = 0.f, hbv = 0.f;
            if (tid < NH) {
                shH[tid] = Hw[t * NH + tid];
                fbv = Fb[t * NH + tid];
            } else if (tid < 192) {
                hbv = Hb[t];
            }

            const f32x4 zero4 = {0.f, 0.f, 0.f, 0.f};
            f32x4 accU[2][2];
#pragma unroll
            for (int rt = 0; rt < 2; ++rt)
#pragma unroll
                for (int ct = 0; ct < 2; ++ct) accU[rt][ct] = zero4;
#pragma unroll
            for (int kc = 0; kc < 4; ++kc) {
#pragma unroll
                for (int rt = 0; rt < 2; ++rt) {
                    bf16x8 ph = *(bf16x8*)&PhiS[(arow + rt * 16 + lm) * SP + kc * 32 + kg * 8];
                    bf16x8 pl = *(bf16x8*)&PloS[(arow + rt * 16 + lm) * SP + kc * 32 + kg * 8];
#pragma unroll
                    for (int ct = 0; ct < 2; ++ct)
                        accU[rt][ct] = mfma3(ph, pl, fbH[ct][kc], fbL[ct][kc], accU[rt][ct]);
                }
            }
            // vec-rows tile (waves a==0): rows 128..130 of X -> fw, fv, Fg
            if (a == 0) {
                f32x4 accV[2];
                accV[0] = zero4; accV[1] = zero4;
#pragma unroll
                for (int kc = 0; kc < 4; ++kc) {
                    bf16x8 vh = *(bf16x8*)&PhiS[(128 + lm) * SP + kc * 32 + kg * 8];
                    bf16x8 vl = *(bf16x8*)&PloS[(128 + lm) * SP + kc * 32 + kg * 8];
#pragma unroll
                    for (int ct = 0; ct < 2; ++ct)
                        accV[ct] = mfma3(vh, vl, fbH[ct][kc], fbL[ct][kc], accV[ct]);
                }
                if (kg == 0) {
#pragma unroll
                    for (int ct = 0; ct < 2; ++ct) {
                        int c = bcol + ct * 16 + lm;
                        shFW[c] = accV[ct][0];     // F w
                        shFV[c] = accV[ct][1];     // F k
                        shGn[c] = accV[ct][2];     // F g
                    }
                }
            }
            // epilogue A: write U^T hi/lo
#pragma unroll
            for (int rt = 0; rt < 2; ++rt)
#pragma unroll
                for (int ct = 0; ct < 2; ++ct) {
                    int Urow = arow + rt * 16 + kg * 4;
                    int Ucol = bcol + ct * 16 + lm;
                    bf16x4 uh, ul;
#pragma unroll
                    for (int reg = 0; reg < 4; ++reg) {
                        float v = accU[rt][ct][reg];
                        __bf16 h = (__bf16)v;
                        uh[reg] = h;
                        ul[reg] = (__bf16)(v - (float)h);
                    }
                    *(bf16x4*)&UhiS[Ucol * SP + Urow] = uh;
                    *(bf16x4*)&UloS[Ucol * SP + Urow] = ul;
                }
            __syncthreads();

            // ====== phase B: P' = Q + F U - fv fw^T ; operand-swapped MFMA ======
            f32x4 accP[2][2];
#pragma unroll
            for (int rt2 = 0; rt2 < 2; ++rt2)
#pragma unroll
                for (int ct2 = 0; ct2 < 2; ++ct2) accP[rt2][ct2] = qreg[rt2][ct2];
#pragma unroll
            for (int kc = 0; kc < 4; ++kc) {
#pragma unroll
                for (int ct2 = 0; ct2 < 2; ++ct2) {
                    bf16x8 uh = *(bf16x8*)&UhiS[(arow + ct2 * 16 + lm) * SP + kc * 32 + kg * 8];
                    bf16x8 ul = *(bf16x8*)&UloS[(arow + ct2 * 16 + lm) * SP + kc * 32 + kg * 8];
#pragma unroll
                    for (int rt2 = 0; rt2 < 2; ++rt2)
                        accP[rt2][ct2] = mfma3(uh, ul, fbH[rt2][kc], fbL[rt2][kc], accP[rt2][ct2]);
                }
            }
            // prefetch F(t+1) into the now-dead fbH/fbL (hides under epi B + C)
            {
                int tn = (t < NLB - 1) ? t + 1 : NLB - 1;
                LOADF(tn)
            }
            // epilogue B: rank-1 subtract, P' store, v/w partials, g update
            {
                float vr[2] = {0.f, 0.f};
                float wc[2][4];
#pragma unroll
                for (int i = 0; i < 2; ++i)
#pragma unroll
                    for (int j = 0; j < 4; ++j) wc[i][j] = 0.f;
#pragma unroll
                for (int rt2 = 0; rt2 < 2; ++rt2) {
                    int R = bcol + rt2 * 16 + lm;
                    float fvr = shFV[R];
                    float hr  = shH[R];
#pragma unroll
                    for (int ct2 = 0; ct2 < 2; ++ct2) {
                        int cb = arow + ct2 * 16 + kg * 4;
                        f32x4 fw4 = *(const f32x4*)&shFW[cb];
                        f32x4 h4  = *(const f32x4*)&shH[cb];
                        bf16x4 ph4, pl4;
#pragma unroll
                        for (int reg = 0; reg < 4; ++reg) {
                            float val = accP[rt2][ct2][reg] - fvr * fw4[reg];
                            __bf16 vh = (__bf16)val;
                            ph4[reg] = vh;
                            pl4[reg] = (__bf16)(val - (float)vh);
                            vr[rt2]      += val * h4[reg];
                            wc[ct2][reg] += val * hr;
                        }
                        *(bf16x4*)&PhiS[R * SP + cb] = ph4;
                        *(bf16x4*)&PloS[R * SP + cb] = pl4;
                    }
                }
#pragma unroll
                for (int rt2 = 0; rt2 < 2; ++rt2) {
                    vr[rt2] += __shfl_xor(vr[rt2], 16);
                    vr[rt2] += __shfl_xor(vr[rt2], 32);
                }
                if (kg == 0)
#pragma unroll
                    for (int rt2 = 0; rt2 < 2; ++rt2)
                        pV[(bcol + rt2 * 16 + lm) * 5 + a] = vr[rt2];
#pragma unroll
                for (int ct2 = 0; ct2 < 2; ++ct2)
#pragma unroll
                    for (int reg = 0; reg < 4; ++reg) {
#pragma unroll
                        for (int off = 1; off < 16; off <<= 1)
                            wc[ct2][reg] += __shfl_xor(wc[ct2][reg], off);
                    }
                if (lm == 0)
#pragma unroll
                    for (int ct2 = 0; ct2 < 2; ++ct2)
#pragma unroll
                        for (int reg = 0; reg < 4; ++reg)
                            pW[(arow + ct2 * 16 + kg * 4 + reg) * 5 + b] = wc[ct2][reg];
            }
            // g update + vec row 130
            if (tid < NH) {
                float g = shGn[tid] + shFV[tid] * scal[1] + fbv;
                shG[tid] = g;
                __bf16 h = (__bf16)g;
                PhiS[130 * SP + tid] = h;
                PloS[130 * SP + tid] = (__bf16)(g - (float)h);
            }
            __syncthreads();

            // ===== phase C: v->s->k + row129 | w + row128 | eps =====
            if (tid < 64) {
                int j0 = tid, j1 = tid + 64;
                float v0 = pV[j0 * 5] + pV[j0 * 5 + 1] + pV[j0 * 5 + 2] + pV[j0 * 5 + 3];
                float v1 = pV[j1 * 5] + pV[j1 * 5 + 1] + pV[j1 * 5 + 2] + pV[j1 * 5 + 3];
                float p = shH[j0] * v0 + shH[j1] * v1;
#pragma unroll
                for (int off = 1; off < 64; off <<= 1) p += __shfl_xor(p, off);
                float s = 1.f / (Rv + p);
                float k0 = v0 * s, k1v = v1 * s;
                shK[j0] = k0; shK[j1] = k1v;
                AGST(KT_OFF + t * 128 + j0, k0);
                AGST(KT_OFF + t * 128 + j1, k1v);
                __bf16 h0 = (__bf16)k0;
                PhiS[129 * SP + j0] = h0;
                PloS[129 * SP + j0] = (__bf16)(k0 - (float)h0);
                __bf16 h1 = (__bf16)k1v;
                PhiS[129 * SP + j1] = h1;
                PloS[129 * SP + j1] = (__bf16)(k1v - (float)h1);
            } else if (tid < 128) {
                int c0 = tid - 64, c1 = tid;
                float w0 = pW[c0 * 5] + pW[c0 * 5 + 1] + pW[c0 * 5 + 2] + pW[c0 * 5 + 3];
                float w1 = pW[c1 * 5] + pW[c1 * 5 + 1] + pW[c1 * 5 + 2] + pW[c1 * 5 + 3];
                __bf16 h0 = (__bf16)w0;
                PhiS[128 * SP + c0] = h0;
                PloS[128 * SP + c0] = (__bf16)(w0 - (float)h0);
                __bf16 h1 = (__bf16)w1;
                PhiS[128 * SP + c1] = h1;
                PloS[128 * SP + c1] = (__bf16)(w1 - (float)h1);
            } else if (tid < 192) {
                int l = tid - 128;
                float p = shH[l] * shG[l] + shH[l + 64] * shG[l + 64];
#pragma unroll
                for (int off = 1; off < 64; off <<= 1) p += __shfl_xor(p, off);
                if (l == 0) scal[1] = -(p + hbv);
            }
            __syncthreads();
        }

        // publish kt[63]; emit g63 (agent stores); signal done
        if (tid == 512)
            __hip_atomic_store(&wsl[SFLAG_I + 63 * 16], MAGIC,
                               __ATOMIC_RELEASE, __HIP_MEMORY_SCOPE_AGENT);
        if (tid < 128) AGST(g63_OFF + tid, shG[tid] + shK[tid] * scal[1]);
        __syncthreads();
        if (tid == 0)
            __hip_atomic_fetch_add(&wsl[FLAG_I], 1, __ATOMIC_RELEASE, __HIP_MEMORY_SCOPE_AGENT);
        return;
    }

    if (wg <= 32) {
        // ---------------- u-chains: u = F_64^T ... F_pt^T h_pt ----------------
        const int pt = 63 + wg;
        float* part = smisc;
        float* shU  = shV;
        if (tid < NH) shU[tid] = Hw[pt * NH + tid];
        if (tid == 0) scal[2] = Hb[pt];
        __syncthreads();

        for (int j = pt; j >= NLB; --j) {
            const float* Fj  = Fw + (size_t)j * 16384;
            const float* fbj = Fb + j * NH;
            if (tid < 64) {
                float a = shU[tid] * fbj[tid] + shU[tid + 64] * fbj[tid + 64];
#pragma unroll
                for (int off = 32; off; off >>= 1) a += __shfl_down(a, off);
                if (tid == 0) scal[2] += a;
            }
            {
                const int c = tid & 127, sgc = tid >> 7;
                float a = 0.f;
                const float* base = Fj + (size_t)(sgc * 16) * 128 + c;
#pragma unroll 4
                for (int i = 0; i < 16; ++i) a += shU[sgc * 16 + i] * base[(size_t)i * 128];
                part[c * 9 + sgc] = a;
            }
            __syncthreads();
            if (tid < 128) {
                float a = 0.f;
#pragma unroll
                for (int s = 0; s < 8; ++s) a += part[tid * 9 + s];
                shU[tid] = a;
            }
            __syncthreads();
        }

        if (tid < NH) AGST(UV_OFF + (wg - 1) * NH + tid, shU[tid]);
        if (tid == 0) AGST(DP_OFF + (wg - 1), scal[2]);
        __syncthreads();
        if (tid == 0)
            __hip_atomic_fetch_add(&wsl[FLAG_I], 1, __ATOMIC_RELEASE, __HIP_MEMORY_SCOPE_AGENT);
        return;
    }

    if (wg <= 96) {
        // -------- fused k2 columns: relaxed-poll + acquire fence --------------
        const int c = wg - 33;
        float* p2  = (float*)dsm;
        float* shX = shHb[0];
        float* shY = shHb[1];

        if (tid == 0) {
            int spins = 0;
            while (__hip_atomic_load(&wsl[SFLAG_I + c * 16],
                                     __ATOMIC_RELAXED, __HIP_MEMORY_SCOPE_AGENT) != MAGIC) {
                __builtin_amdgcn_s_sleep(8);
                if (++spins > (1 << 20)) break;
            }
            __builtin_amdgcn_fence(__ATOMIC_ACQUIRE, "agent");
        }
        __syncthreads();
        if (tid < 128) shX[tid] = AGLD(KT_OFF + c * 128 + tid);
        __syncthreads();

        for (int j = c + 1; j < NLB; ++j) {
            const float* Fj = Fw + (size_t)j * 16384;
            {
                int r = tid & 127, sg = tid >> 7;
                float a = 0.f;
                const float4* fr = (const float4*)(Fj + r * 128 + sg * 16);
#pragma unroll
                for (int q = 0; q < 4; ++q) {
                    float4 f = fr[q];
                    int m = sg * 16 + q * 4;
                    a += f.x * shX[m] + f.y * shX[m+1] + f.z * shX[m+2] + f.w * shX[m+3];
                }
                p2[sg * 128 + r] = a;
            }
            __syncthreads();
            if (tid < 128) {
                float y = 0.f;
#pragma unroll
                for (int s = 0; s < 8; ++s) y += p2[s * 128 + tid];
                shY[tid] = y;
            }
            __syncthreads();
            if (tid < 64) {
                float a = Hw[j * 128 + 2*tid] * shY[2*tid] + Hw[j * 128 + 2*tid + 1] * shY[2*tid + 1];
#pragma unroll
                for (int off = 32; off; off >>= 1) a += __shfl_down(a, off);
                if (tid == 0) scal[0] = a;
            }
            __syncthreads();
            if (tid == 0) {
                int spins = 0;
                while (__hip_atomic_load(&wsl[SFLAG_I + j * 16],
                                         __ATOMIC_RELAXED, __HIP_MEMORY_SCOPE_AGENT) != MAGIC) {
                    __builtin_amdgcn_s_sleep(8);
                    if (++spins > (1 << 20)) break;
                }
                __builtin_amdgcn_fence(__ATOMIC_ACQUIRE, "agent");
            }
            __syncthreads();
            if (tid < 128) {
                float ktj = AGLD(KT_OFF + j * 128 + tid);
                shX[tid] = shY[tid] - ktj * scal[0];
            }
            __syncthreads();
        }

        if (tid < 128) AGST(XC_OFF + c * 128 + tid, shX[tid]);
        __syncthreads();
        if (tid == 0)
            __hip_atomic_fetch_add(&wsl[FLAG_I], 1, __ATOMIC_RELEASE, __HIP_MEMORY_SCOPE_AGENT);
        return;
    }

    if (wg <= 128) {
        // -------- fused k3: wait for all 97 producers, then M/d + batch GEMM --
        const int wgb = wg - 97;
        float* sUV = (float*)dsm;            // 4096
        float* sXC = sUV + 4096;             // 8192
        float* sG  = sXC + 8192;             // 128
        float* sDP = sG + 128;               // 32
        float* Ml  = sDP + 32;               // 32*65
        float* dl  = Ml + NPW * 65;          // 32

        // burn-poll (keeps clocks up, relaxed loads don't invalidate)
        {
            const int lane = tid & 63;
            float r0 = 1.f + (float)tid * 1e-6f;
            int rounds = 0;
            while (true) {
#pragma unroll 8
                for (int i = 0; i < 512; ++i) r0 = __builtin_fmaf(r0, 0.99999988f, 1.0e-7f);
                int done = 0;
                if (lane == 0)
                    done = (__hip_atomic_load(&wsl[FLAG_I], __ATOMIC_RELAXED,
                                              __HIP_MEMORY_SCOPE_AGENT) >= 97);
                done = __shfl(done, 0);
                if (done || ++rounds > (1 << 15)) break;
            }
            if (r0 == 123.4567f) ws[SINK_OFF + wg] = r0;
            if (tid == 0) __builtin_amdgcn_fence(__ATOMIC_ACQUIRE, "agent");
        }
        __syncthreads();

        // stage UV/XC/g63/DP into LDS via agent loads
        for (int i = tid; i < 4096; i += 1024) sUV[i] = AGLD(UV_OFF + i);
        for (int i = tid; i < 8192; i += 1024) sXC[i] = AGLD(XC_OFF + i);
        if (tid < 128) sG[tid] = AGLD(g63_OFF + tid);
        else if (tid < 160) sDP[tid - 128] = AGLD(DP_OFF + (tid - 128));
        __syncthreads();

        // d
        {
            int p = tid >> 5, l = tid & 31;
            float a = 0.f;
#pragma unroll
            for (int q = 0; q < 4; ++q)
                a += sUV[p * 128 + l + q * 32] * sG[l + q * 32];
#pragma unroll
            for (int off = 1; off < 32; off <<= 1) a += __shfl_xor(a, off);
            if (l == 0) dl[p] = sDP[p] + a;
        }
        // M
        {
            int p0 = tid >> 6, n = tid & 63;
            const float4* xc = (const float4*)&sXC[n * 128];
#pragma unroll
            for (int pp = 0; pp < 2; ++pp) {
                int p = p0 + pp * 16;
                const float4* up = (const float4*)&sUV[p * 128];
                float a = 0.f;
#pragma unroll
                for (int q = 0; q < 32; ++q) {
                    float4 u4 = up[q]; float4 c4 = xc[q];
                    a += u4.x * c4.x + u4.y * c4.y + u4.z * c4.z + u4.w * c4.w;
                }
                Ml[p * 65 + n] = a;
            }
        }
        __syncthreads();

        // batch GEMM slice
        {
            const int r  = wgb * 256 + (tid >> 2);
            const int pg = tid & 3;
            float acc[8];
#pragma unroll
            for (int pi = 0; pi < 8; ++pi) acc[pi] = dl[pg * 8 + pi];
            const float4* xr = (const float4*)(x + (size_t)r * 64);
#pragma unroll
            for (int c4 = 0; c4 < 16; ++c4) {
                float4 xv = xr[c4];
#pragma unroll
                for (int pi = 0; pi < 8; ++pi) {
                    const float* mrow = &Ml[(pg * 8 + pi) * 65 + c4 * 4];
                    acc[pi] += xv.x * mrow[0] + xv.y * mrow[1] + xv.z * mrow[2] + xv.w * mrow[3];
                }
            }
            float* op = out + (size_t)r * 32 + pg * 8;
            *(float4*)op       = make_float4(acc[0], acc[1], acc[2], acc[3]);
            *(float4*)(op + 4) = make_float4(acc[4], acc[5], acc[6], acc[7]);
        }
        return;
    }

    // -------- slim burners: 4 waves/CU, no barriers, bounded spin ------------
    {
        if (tid >= 256) return;
        const int lane = tid & 63;
        float r0 = 1.f + (float)tid * 1e-6f + (float)wg * 1e-5f;
        int rounds = 0;
        while (true) {
#pragma unroll 8
            for (int i = 0; i < 1024; ++i) r0 = __builtin_fmaf(r0, 0.99999988f, 1.0e-7f);
            int done = 0;
            if (lane == 0)
                done = (__hip_atomic_load(&wsl[FLAG_I], __ATOMIC_RELAXED,
                                          __HIP_MEMORY_SCOPE_AGENT) >= 97);
            done = __shfl(done, 0);
            if (done || ++rounds > 8192) break;
        }
        if (r0 == 123.4567f) ws[SINK_OFF + wg] = r0;   // never true; defeats DCE
    }
}

extern "C" void kernel_launch(void* const* d_in, const int* in_sizes, int n_in,
                              void* d_out, int out_size, void* d_ws, size_t ws_size,
                              hipStream_t stream) {
    const float* x          = (const float*)d_in[0];
    const float* F_w        = (const float*)d_in[1];
    const float* F_b        = (const float*)d_in[2];
    const float* H_w        = (const float*)d_in[3];
    const float* H_b        = (const float*)d_in[4];
    const float* init_state = (const float*)d_in[5];
    const float* init_cov   = (const float*)d_in[6];
    const float* Qm         = (const float*)d_in[7];
    const float* Rm         = (const float*)d_in[8];
    float* ws   = (float*)d_ws;
    float* outp = (float*)d_out;

    int use_split = (ws_size >= WS_SPLIT_BYTES + 65536) ? 1 : 0;

    (void)hipFuncSetAttribute((const void*)k1_recur,
                              hipFuncAttributeMaxDynamicSharedMemorySize, DYN_LDS);

    if (use_split)
        k0_split<<<dim3(512), dim3(256), 0, stream>>>(F_w, ws);
    k1_recur<<<dim3(256), dim3(1024), DYN_LDS, stream>>>(
        F_w, F_b, H_w, H_b, init_state, init_cov, Qm, Rm, x, outp, ws, use_split);
}

// Round 8
// 1092.865 us; speedup vs baseline: 75.4144x; 75.4144x over previous
//
#include <hip/hip_runtime.h>

#define NB 8192
#define NH 128
#define NLB 64
#define NPW 32
#define MAGIC 1234567
#define SP 136                      // LDS stride (bf16): 272B rows, 16B-aligned

typedef __attribute__((ext_vector_type(8))) __bf16 bf16x8;
typedef __attribute__((ext_vector_type(4))) __bf16 bf16x4;
typedef __attribute__((ext_vector_type(4))) float f32x4;

__device__ __forceinline__ f32x4 mfma3(bf16x8 ah, bf16x8 al, bf16x8 bh, bf16x8 bl, f32x4 c) {
    c = __builtin_amdgcn_mfma_f32_16x16x32_bf16(ah, bh, c, 0, 0, 0);
    c = __builtin_amdgcn_mfma_f32_16x16x32_bf16(ah, bl, c, 0, 0, 0);
    c = __builtin_amdgcn_mfma_f32_16x16x32_bf16(al, bh, c, 0, 0, 0);
    return c;
}

__device__ __forceinline__ void ld_split8(const float* p, bf16x8& h, bf16x8& l) {
    float vv[8];
    *(float4*)vv       = *(const float4*)p;
    *(float4*)(vv + 4) = *(const float4*)(p + 4);
#pragma unroll
    for (int j = 0; j < 8; ++j) {
        __bf16 t = (__bf16)vv[j];
        h[j] = t;
        l[j] = (__bf16)(vv[j] - (float)t);
    }
}

// ws float offsets
#define KT_OFF   560                  // 64*128 k-table
#define g63_OFF  (KT_OFF + 8192)
#define MR_OFF   (g63_OFF + 128)      // legacy M region (unused)
#define DV_OFF   (MR_OFF + 2048)
#define DP_OFF   (DV_OFF + 32)
#define UV_OFF   (DP_OFF + 32)        // 32*128 u-vectors
#define XC_OFF   16000                // 64*128 X-columns (fused k2 output)
#define SINK_OFF 32000
#define FLAG_I   34000                // int index (legacy area)
#define SFLAG_I  (FLAG_I + 1600)      // per-step flags: SFLAG_I + t*16, value MAGIC
#define FHI_OFF  40960                // bf16 hi of F[0..63]: 1M ushort = 524288 floats
#define FLO_OFF  (FHI_OFF + 524288)
#define WS_SPLIT_BYTES  ((size_t)(FLO_OFF + 524288) * 4)

// X(hi/lo): 144 rows (128 P + w/k/g + pad) ; U^T(hi/lo): 128 rows
#define DYN_LDS  ((144 + 144 + 128 + 128) * SP * 2)   // 147968 B

// ========== K0: pre-split F[t<64] into bf16 hi/lo ===========================
__global__ __launch_bounds__(256)
void k0_split(const float* __restrict__ F, float* __restrict__ ws)
{
    size_t e = ((size_t)blockIdx.x * 256 + threadIdx.x) * 8;
    __bf16* fh = (__bf16*)(ws + FHI_OFF);
    __bf16* fl = (__bf16*)(ws + FLO_OFF);
    float v[8];
    *(float4*)v       = *(const float4*)(F + e);
    *(float4*)(v + 4) = *(const float4*)(F + e + 4);
    bf16x8 h, l;
#pragma unroll
    for (int j = 0; j < 8; ++j) {
        __bf16 t = (__bf16)v[j];
        h[j] = t;
        l[j] = (__bf16)(v[j] - (float)t);
    }
    *(bf16x8*)&fh[e] = h;
    *(bf16x8*)&fl[e] = l;
}

// ========== K1: recursion (wg0) + u-chains + fused columns + burners ========
__global__ __launch_bounds__(1024) __attribute__((amdgpu_waves_per_eu(4, 4)))
void k1_recur(const float* __restrict__ Fw,
              const float* __restrict__ Fb,
              const float* __restrict__ Hw,
              const float* __restrict__ Hb,
              const float* __restrict__ init_state,
              const float* __restrict__ init_cov,
              const float* __restrict__ Qm,
              const float* __restrict__ Rm,
              float* __restrict__ ws,
              int use_split)
{
    const int tid = threadIdx.x;
    const int wg  = blockIdx.x;
    int* wsl = (int*)ws;

    extern __shared__ __align__(16) char dsm[];
    __bf16* PhiS = (__bf16*)dsm;                 // X hi: [144][SP] (rows 128..130 = w,k,g)
    __bf16* PloS = PhiS + 144 * SP;
    __bf16* UhiS = PloS + 144 * SP;              // U^T hi: [c:128][i:SP]
    __bf16* UloS = UhiS + 128 * SP;

    __shared__ float smisc[1280];                // pV[640] | pW[640]; u-chain partials
    __shared__ __align__(16) float shHb[2][NH];  // columns: shX/shY
    __shared__ __align__(16) float shH[NH];
    __shared__ __align__(16) float shFW[NH];
    __shared__ float shK[NH], shV[NH], shFV[NH], shG[NH], shGn[NH];
    __shared__ float scal[16];

    float* pV = smisc;            // [r*5 + a]
    float* pW = smisc + 640;      // [c*5 + b]

    if (wg == 0) {
        const float Rv = Rm[0];
        const int lane = tid & 63, w = tid >> 6;
        const int lm = lane & 15, kg = lane >> 4;
        const int a = w >> 2, b = w & 3;          // 4x4 wave grid
        const int arow = a * 32, bcol = b * 32;

        // ---- init: X rows 0..127 = init_cov (hi/lo) ----
#pragma unroll
        for (int ii = 0; ii < 16; ++ii) {
            int e = tid + ii * 1024;
            int r = e >> 7, c = e & 127;
            float v = init_cov[e];
            __bf16 h = (__bf16)v;
            PhiS[r * SP + c] = h;
            PloS[r * SP + c] = (__bf16)(v - (float)h);
        }
        // ---- init: X rows 128..143: w=0, k=0, g=init_state, rest 0 ----
#pragma unroll
        for (int ii = 0; ii < 2; ++ii) {
            int e = tid + ii * 1024;
            int r = 128 + (e >> 7), c = e & 127;
            float v = (r == 130) ? init_state[c] : 0.f;
            __bf16 h = (__bf16)v;
            PhiS[r * SP + c] = h;
            PloS[r * SP + c] = (__bf16)(v - (float)h);
        }
        if (tid < NH) shG[tid] = init_state[tid];
        if (tid == 0) scal[1] = 0.f;

        // Q tile in registers across the whole t-loop (phase-B output map).
        f32x4 qreg[2][2];
#pragma unroll
        for (int rt2 = 0; rt2 < 2; ++rt2)
#pragma unroll
            for (int ct2 = 0; ct2 < 2; ++ct2)
                qreg[rt2][ct2] =
                    *(const f32x4*)&Qm[(bcol + rt2 * 16 + lm) * 128 + arow + ct2 * 16 + kg * 4];
        __syncthreads();

        for (int t = 0; t < NLB; ++t) {
            // publish kt[t-1] (ordered by the loop-end barrier of step t-1)
            if (t && tid == 512)
                __hip_atomic_store(&wsl[SFLAG_I + (t - 1) * 16], MAGIC,
                                   __ATOMIC_RELEASE, __HIP_MEMORY_SCOPE_AGENT);

            // ================= phase A: U = X F^T (U^T -> LDS) =================
            float fbv = 0.f, hbv = 0.f;
            if (tid < NH) {
                shH[tid] = Hw[t * NH + tid];
                fbv = Fb[t * NH + tid];
            } else if (tid < 192) {
                hbv = Hb[t];
            }
            bf16x8 fbH[2][4], fbL[2][4];           // F rows [bcol, bcol+32)
            if (use_split) {
                const __bf16* fh = (const __bf16*)(ws + FHI_OFF) + (size_t)t * 16384;
                const __bf16* fl = (const __bf16*)(ws + FLO_OFF) + (size_t)t * 16384;
#pragma unroll
                for (int rs = 0; rs < 2; ++rs)
#pragma unroll
                    for (int kc = 0; kc < 4; ++kc) {
                        int ro = (bcol + rs * 16 + lm) * 128 + kc * 32 + kg * 8;
                        fbH[rs][kc] = *(const bf16x8*)&fh[ro];
                        fbL[rs][kc] = *(const bf16x8*)&fl[ro];
                    }
            } else {
                const float* Ft = Fw + (size_t)t * 16384;
#pragma unroll
                for (int rs = 0; rs < 2; ++rs)
#pragma unroll
                    for (int kc = 0; kc < 4; ++kc)
                        ld_split8(Ft + (bcol + rs * 16 + lm) * 128 + kc * 32 + kg * 8,
                                  fbH[rs][kc], fbL[rs][kc]);
            }

            const f32x4 zero4 = {0.f, 0.f, 0.f, 0.f};
            f32x4 accU[2][2];
#pragma unroll
            for (int rt = 0; rt < 2; ++rt)
#pragma unroll
                for (int ct = 0; ct < 2; ++ct) accU[rt][ct] = zero4;
#pragma unroll
            for (int kc = 0; kc < 4; ++kc) {
#pragma unroll
                for (int rt = 0; rt < 2; ++rt) {
                    bf16x8 ph = *(bf16x8*)&PhiS[(arow + rt * 16 + lm) * SP + kc * 32 + kg * 8];
                    bf16x8 pl = *(bf16x8*)&PloS[(arow + rt * 16 + lm) * SP + kc * 32 + kg * 8];
#pragma unroll
                    for (int ct = 0; ct < 2; ++ct)
                        accU[rt][ct] = mfma3(ph, pl, fbH[ct][kc], fbL[ct][kc], accU[rt][ct]);
                }
            }
            // vec-rows tile (waves a==0): rows 128..130 of X -> fw, fv, Fg
            if (a == 0) {
                f32x4 accV[2];
                accV[0] = zero4; accV[1] = zero4;
#pragma unroll
                for (int kc = 0; kc < 4; ++kc) {
                    bf16x8 vh = *(bf16x8*)&PhiS[(128 + lm) * SP + kc * 32 + kg * 8];
                    bf16x8 vl = *(bf16x8*)&PloS[(128 + lm) * SP + kc * 32 + kg * 8];
#pragma unroll
                    for (int ct = 0; ct < 2; ++ct)
                        accV[ct] = mfma3(vh, vl, fbH[ct][kc], fbL[ct][kc], accV[ct]);
                }
                if (kg == 0) {
#pragma unroll
                    for (int ct = 0; ct < 2; ++ct) {
                        int c = bcol + ct * 16 + lm;
                        shFW[c] = accV[ct][0];     // F w
                        shFV[c] = accV[ct][1];     // F k
                        shGn[c] = accV[ct][2];     // F g
                    }
                }
            }
            // epilogue A: write U^T hi/lo (contiguous bf16x4 along U-row)
#pragma unroll
            for (int rt = 0; rt < 2; ++rt)
#pragma unroll
                for (int ct = 0; ct < 2; ++ct) {
                    int Urow = arow + rt * 16 + kg * 4;
                    int Ucol = bcol + ct * 16 + lm;
                    bf16x4 uh, ul;
#pragma unroll
                    for (int reg = 0; reg < 4; ++reg) {
                        float v = accU[rt][ct][reg];
                        __bf16 h = (__bf16)v;
                        uh[reg] = h;
                        ul[reg] = (__bf16)(v - (float)h);
                    }
                    *(bf16x4*)&UhiS[Ucol * SP + Urow] = uh;
                    *(bf16x4*)&UloS[Ucol * SP + Urow] = ul;
                }
            __syncthreads();

            // ====== phase B: P' = Q + F U - fv fw^T ; operand-swapped MFMA ======
            f32x4 accP[2][2];
#pragma unroll
            for (int rt2 = 0; rt2 < 2; ++rt2)
#pragma unroll
                for (int ct2 = 0; ct2 < 2; ++ct2) accP[rt2][ct2] = qreg[rt2][ct2];
#pragma unroll
            for (int kc = 0; kc < 4; ++kc) {
#pragma unroll
                for (int ct2 = 0; ct2 < 2; ++ct2) {
                    bf16x8 uh = *(bf16x8*)&UhiS[(arow + ct2 * 16 + lm) * SP + kc * 32 + kg * 8];
                    bf16x8 ul = *(bf16x8*)&UloS[(arow + ct2 * 16 + lm) * SP + kc * 32 + kg * 8];
#pragma unroll
                    for (int rt2 = 0; rt2 < 2; ++rt2)
                        accP[rt2][ct2] = mfma3(uh, ul, fbH[rt2][kc], fbL[rt2][kc], accP[rt2][ct2]);
                }
            }
            // epilogue B: rank-1 subtract, vectorized P' store, v/w partials, g update
            {
                float vr[2] = {0.f, 0.f};
                float wc[2][4];
#pragma unroll
                for (int i = 0; i < 2; ++i)
#pragma unroll
                    for (int j = 0; j < 4; ++j) wc[i][j] = 0.f;
#pragma unroll
                for (int rt2 = 0; rt2 < 2; ++rt2) {
                    int R = bcol + rt2 * 16 + lm;
                    float fvr = shFV[R];
                    float hr  = shH[R];
#pragma unroll
                    for (int ct2 = 0; ct2 < 2; ++ct2) {
                        int cb = arow + ct2 * 16 + kg * 4;
                        f32x4 fw4 = *(const f32x4*)&shFW[cb];
                        f32x4 h4  = *(const f32x4*)&shH[cb];
                        bf16x4 ph4, pl4;
#pragma unroll
                        for (int reg = 0; reg < 4; ++reg) {
                            float val = accP[rt2][ct2][reg] - fvr * fw4[reg];
                            __bf16 vh = (__bf16)val;
                            ph4[reg] = vh;
                            pl4[reg] = (__bf16)(val - (float)vh);
                            vr[rt2]      += val * h4[reg];
                            wc[ct2][reg] += val * hr;
                        }
                        *(bf16x4*)&PhiS[R * SP + cb] = ph4;
                        *(bf16x4*)&PloS[R * SP + cb] = pl4;
                    }
                }
#pragma unroll
                for (int rt2 = 0; rt2 < 2; ++rt2) {
                    vr[rt2] += __shfl_xor(vr[rt2], 16);
                    vr[rt2] += __shfl_xor(vr[rt2], 32);
                }
                if (kg == 0)
#pragma unroll
                    for (int rt2 = 0; rt2 < 2; ++rt2)
                        pV[(bcol + rt2 * 16 + lm) * 5 + a] = vr[rt2];
#pragma unroll
                for (int ct2 = 0; ct2 < 2; ++ct2)
#pragma unroll
                    for (int reg = 0; reg < 4; ++reg) {
#pragma unroll
                        for (int off = 1; off < 16; off <<= 1)
                            wc[ct2][reg] += __shfl_xor(wc[ct2][reg], off);
                    }
                if (lm == 0)
#pragma unroll
                    for (int ct2 = 0; ct2 < 2; ++ct2)
#pragma unroll
                        for (int reg = 0; reg < 4; ++reg)
                            pW[(arow + ct2 * 16 + kg * 4 + reg) * 5 + b] = wc[ct2][reg];
            }
            // g update + vec row 130 (fbv prefetched in phase A)
            if (tid < NH) {
                float g = shGn[tid] + shFV[tid] * scal[1] + fbv;
                shG[tid] = g;
                __bf16 h = (__bf16)g;
                PhiS[130 * SP + tid] = h;
                PloS[130 * SP + tid] = (__bf16)(g - (float)h);
            }
            __syncthreads();

            // ===== phase C (merged): v->s->k + row129 | w + row128 | eps =====
            if (tid < 64) {
                int j0 = tid, j1 = tid + 64;
                float v0 = pV[j0 * 5] + pV[j0 * 5 + 1] + pV[j0 * 5 + 2] + pV[j0 * 5 + 3];
                float v1 = pV[j1 * 5] + pV[j1 * 5 + 1] + pV[j1 * 5 + 2] + pV[j1 * 5 + 3];
                float p = shH[j0] * v0 + shH[j1] * v1;
#pragma unroll
                for (int off = 1; off < 64; off <<= 1) p += __shfl_xor(p, off);
                float s = 1.f / (Rv + p);
                float k0 = v0 * s, k1v = v1 * s;
                shK[j0] = k0; shK[j1] = k1v;
                __hip_atomic_store(&ws[KT_OFF + t * 128 + j0], k0,
                                   __ATOMIC_RELAXED, __HIP_MEMORY_SCOPE_AGENT);
                __hip_atomic_store(&ws[KT_OFF + t * 128 + j1], k1v,
                                   __ATOMIC_RELAXED, __HIP_MEMORY_SCOPE_AGENT);
                __bf16 h0 = (__bf16)k0;
                PhiS[129 * SP + j0] = h0;
                PloS[129 * SP + j0] = (__bf16)(k0 - (float)h0);
                __bf16 h1 = (__bf16)k1v;
                PhiS[129 * SP + j1] = h1;
                PloS[129 * SP + j1] = (__bf16)(k1v - (float)h1);
            } else if (tid < 128) {
                int c0 = tid - 64, c1 = tid;
                float w0 = pW[c0 * 5] + pW[c0 * 5 + 1] + pW[c0 * 5 + 2] + pW[c0 * 5 + 3];
                float w1 = pW[c1 * 5] + pW[c1 * 5 + 1] + pW[c1 * 5 + 2] + pW[c1 * 5 + 3];
                __bf16 h0 = (__bf16)w0;
                PhiS[128 * SP + c0] = h0;
                PloS[128 * SP + c0] = (__bf16)(w0 - (float)h0);
                __bf16 h1 = (__bf16)w1;
                PhiS[128 * SP + c1] = h1;
                PloS[128 * SP + c1] = (__bf16)(w1 - (float)h1);
            } else if (tid < 192) {
                int l = tid - 128;
                float p = shH[l] * shG[l] + shH[l + 64] * shG[l + 64];
#pragma unroll
                for (int off = 1; off < 64; off <<= 1) p += __shfl_xor(p, off);
                if (l == 0) scal[1] = -(p + hbv);
            }
            __syncthreads();
        }

        // publish kt[63] (ordered by the final loop barrier), emit g63
        if (tid == 512)
            __hip_atomic_store(&wsl[SFLAG_I + 63 * 16], MAGIC,
                               __ATOMIC_RELEASE, __HIP_MEMORY_SCOPE_AGENT);
        if (tid < 128) ws[g63_OFF + tid] = shG[tid] + shK[tid] * scal[1];
        return;
    }

    if (wg <= 32) {
        // ---------------- u-chains: u = F_64^T ... F_pt^T h_pt ----------------
        const int pt = 63 + wg;
        float* part = smisc;
        float* shU  = shV;
        if (tid < NH) shU[tid] = Hw[pt * NH + tid];
        if (tid == 0) scal[2] = Hb[pt];
        __syncthreads();

        for (int j = pt; j >= NLB; --j) {
            const float* Fj  = Fw + (size_t)j * 16384;
            const float* fbj = Fb + j * NH;
            if (tid < 64) {
                float a = shU[tid] * fbj[tid] + shU[tid + 64] * fbj[tid + 64];
#pragma unroll
                for (int off = 32; off; off >>= 1) a += __shfl_down(a, off);
                if (tid == 0) scal[2] += a;
            }
            {
                const int c = tid & 127, sgc = tid >> 7;
                float a = 0.f;
                const float* base = Fj + (size_t)(sgc * 16) * 128 + c;
#pragma unroll 4
                for (int i = 0; i < 16; ++i) a += shU[sgc * 16 + i] * base[(size_t)i * 128];
                part[c * 9 + sgc] = a;
            }
            __syncthreads();
            if (tid < 128) {
                float a = 0.f;
#pragma unroll
                for (int s = 0; s < 8; ++s) a += part[tid * 9 + s];
                shU[tid] = a;
            }
            __syncthreads();
        }

        if (tid < NH) ws[UV_OFF + (wg - 1) * NH + tid] = shU[tid];
        if (tid == 0) ws[DP_OFF + (wg - 1)] = scal[2];
        return;     // consumed by k3 (next launch)
    }

    if (wg <= 96) {
        // -------- fused k2 columns: X_c chain, relaxed-poll + acquire fence ---
        const int c = wg - 33;
        float* p2  = (float*)dsm;          // 1024-float scratch
        float* shX = shHb[0];
        float* shY = shHb[1];

        // wait for kt[c] (relaxed spin, one acquire fence after)
        if (tid == 0) {
            int spins = 0;
            while (__hip_atomic_load(&wsl[SFLAG_I + c * 16],
                                     __ATOMIC_RELAXED, __HIP_MEMORY_SCOPE_AGENT) != MAGIC) {
                __builtin_amdgcn_s_sleep(8);
                if (++spins > (1 << 20)) break;
            }
            __builtin_amdgcn_fence(__ATOMIC_ACQUIRE, "agent");
        }
        __syncthreads();
        if (tid < 128)
            shX[tid] = __hip_atomic_load(&ws[KT_OFF + c * 128 + tid],
                                         __ATOMIC_RELAXED, __HIP_MEMORY_SCOPE_AGENT);
        __syncthreads();

        for (int j = c + 1; j < NLB; ++j) {
            // y = F_j · X  (does not need kt[j])
            const float* Fj = Fw + (size_t)j * 16384;
            {
                int r = tid & 127, sg = tid >> 7;
                float a = 0.f;
                const float4* fr = (const float4*)(Fj + r * 128 + sg * 16);
#pragma unroll
                for (int q = 0; q < 4; ++q) {
                    float4 f = fr[q];
                    int m = sg * 16 + q * 4;
                    a += f.x * shX[m] + f.y * shX[m+1] + f.z * shX[m+2] + f.w * shX[m+3];
                }
                p2[sg * 128 + r] = a;
            }
            __syncthreads();
            if (tid < 128) {
                float y = 0.f;
#pragma unroll
                for (int s = 0; s < 8; ++s) y += p2[s * 128 + tid];
                shY[tid] = y;
            }
            __syncthreads();
            if (tid < 64) {
                float a = Hw[j * 128 + 2*tid] * shY[2*tid] + Hw[j * 128 + 2*tid + 1] * shY[2*tid + 1];
#pragma unroll
                for (int off = 32; off; off >>= 1) a += __shfl_down(a, off);
                if (tid == 0) scal[0] = a;
            }
            __syncthreads();
            // wait for kt[j], then X = y - kt[j] * (h·y)
            if (tid == 0) {
                int spins = 0;
                while (__hip_atomic_load(&wsl[SFLAG_I + j * 16],
                                         __ATOMIC_RELAXED, __HIP_MEMORY_SCOPE_AGENT) != MAGIC) {
                    __builtin_amdgcn_s_sleep(8);
                    if (++spins > (1 << 20)) break;
                }
                __builtin_amdgcn_fence(__ATOMIC_ACQUIRE, "agent");
            }
            __syncthreads();
            if (tid < 128) {
                float ktj = __hip_atomic_load(&ws[KT_OFF + j * 128 + tid],
                                              __ATOMIC_RELAXED, __HIP_MEMORY_SCOPE_AGENT);
                shX[tid] = shY[tid] - ktj * scal[0];
            }
            __syncthreads();
        }

        if (tid < 128) ws[XC_OFF + c * 128 + tid] = shX[tid];   // consumed by k3
        return;
    }

    // -------- slim burners: 4 waves/CU, no barriers, bounded spin ------------
    {
        if (tid >= 256) return;
        const int lane = tid & 63;
        float r0 = 1.f + (float)tid * 1e-6f + (float)wg * 1e-5f;
        int rounds = 0;
        while (true) {
#pragma unroll 8
            for (int i = 0; i < 1024; ++i) r0 = __builtin_fmaf(r0, 0.99999988f, 1.0e-7f);
            int done = 0;
            if (lane == 0)
                done = (__hip_atomic_load(&wsl[SFLAG_I + 63 * 16],
                                          __ATOMIC_RELAXED, __HIP_MEMORY_SCOPE_AGENT) == MAGIC);
            done = __shfl(done, 0);
            if (done || ++rounds > 8192) break;
        }
        if (r0 == 123.4567f) ws[SINK_OFF + wg] = r0;   // never true; defeats DCE
    }
}

// ========== K3: d + M (from UV, XC) + batch GEMM ============================
__global__ __launch_bounds__(1024)
void k3_batch(const float* __restrict__ x,
              const float* __restrict__ ws,
              float* __restrict__ out)
{
    const int tid = threadIdx.x;
    const int wgb = blockIdx.x;
    __shared__ float Ml[NPW * 65];
    __shared__ float dl[NPW];

    // ---- d: dl[p] = DP[p] + UV[p]·g63 ----
    {
        int p = tid >> 5, l = tid & 31;
        float a = 0.f;
#pragma unroll
        for (int q = 0; q < 4; ++q)
            a += ws[UV_OFF + p * 128 + l + q * 32] * ws[g63_OFF + l + q * 32];
#pragma unroll
        for (int off = 1; off < 32; off <<= 1) a += __shfl_xor(a, off);
        if (l == 0) dl[p] = ws[DP_OFF + p] + a;
    }
    // ---- M: Ml[p][n] = UV[p]·XC[n] ----
    {
        int p0 = tid >> 6, n = tid & 63;
        const float4* xc = (const float4*)&ws[XC_OFF + n * 128];
#pragma unroll
        for (int pp = 0; pp < 2; ++pp) {
            int p = p0 + pp * 16;
            const float4* up = (const float4*)&ws[UV_OFF + p * 128];
            float a = 0.f;
#pragma unroll
            for (int q = 0; q < 32; ++q) {
                float4 u4 = up[q]; float4 c4 = xc[q];
                a += u4.x * c4.x + u4.y * c4.y + u4.z * c4.z + u4.w * c4.w;
            }
            Ml[p * 65 + n] = a;
        }
    }
    __syncthreads();

    const int r  = wgb * 256 + (tid >> 2);
    const int pg = tid & 3;
    float acc[8];
#pragma unroll
    for (int pi = 0; pi < 8; ++pi) acc[pi] = dl[pg * 8 + pi];
    const float4* xr = (const float4*)(x + (size_t)r * 64);
#pragma unroll
    for (int c4 = 0; c4 < 16; ++c4) {
        float4 xv = xr[c4];
#pragma unroll
        for (int pi = 0; pi < 8; ++pi) {
            const float* mrow = &Ml[(pg * 8 + pi) * 65 + c4 * 4];
            acc[pi] += xv.x * mrow[0] + xv.y * mrow[1] + xv.z * mrow[2] + xv.w * mrow[3];
        }
    }
    float* op = out + (size_t)r * 32 + pg * 8;
    *(float4*)op       = make_float4(acc[0], acc[1], acc[2], acc[3]);
    *(float4*)(op + 4) = make_float4(acc[4], acc[5], acc[6], acc[7]);
}

extern "C" void kernel_launch(void* const* d_in, const int* in_sizes, int n_in,
                              void* d_out, int out_size, void* d_ws, size_t ws_size,
                              hipStream_t stream) {
    const float* x          = (const float*)d_in[0];
    const float* F_w        = (const float*)d_in[1];
    const float* F_b        = (const float*)d_in[2];
    const float* H_w        = (const float*)d_in[3];
    const float* H_b        = (const float*)d_in[4];
    const float* init_state = (const float*)d_in[5];
    const float* init_cov   = (const float*)d_in[6];
    const float* Qm         = (const float*)d_in[7];
    const float* Rm         = (const float*)d_in[8];
    float* ws   = (float*)d_ws;
    float* outp = (float*)d_out;

    int use_split = (ws_size >= WS_SPLIT_BYTES + 65536) ? 1 : 0;

    (void)hipFuncSetAttribute((const void*)k1_recur,
                              hipFuncAttributeMaxDynamicSharedMemorySize, DYN_LDS);

    if (use_split)
        k0_split<<<dim3(512), dim3(256), 0, stream>>>(F_w, ws);
    k1_recur<<<dim3(256), dim3(1024), DYN_LDS, stream>>>(
        F_w, F_b, H_w, H_b, init_state, init_cov, Qm, Rm, ws, use_split);
    k3_batch<<<dim3(32), dim3(1024), 0, stream>>>(x, ws, outp);
}